// Round 6
// baseline (375.560 us; speedup 1.0000x reference)
//
#include <hip/hip_runtime.h>
#include <math.h>

// MoE FFN, routed (top-2 pair-grouped), BK=128 "LDS-image" formulation.
//   All GEMM operands live as pre-swizzled 32 KB images [128 rows x 128 k]:
//     elem(r, k) at  r*128 + (((k>>3) ^ (r&15)) << 3) + (k&7)
//   so staging = contiguous memcpy via global_load_lds, and ds_read_b128
//   fragment reads are bank-conflict-free (granule XOR key = row&15 = l16).
//   G1: Tp images = X[tok] @ w1pair * scale   (A gathered from xb)
//   G2: Hbp images = gelu(Tp @ w2pair)        (4 K-iters, K=512)
//   G3: out = Hbp @ lin2_w^T + bias           (32 K-iters, XCD-owned M groups)

using short8  = __attribute__((ext_vector_type(8))) short;
using floatx4 = __attribute__((ext_vector_type(4))) float;
typedef unsigned short bf16_t;

#define TOK   8192
#define HDIM  1024
#define RDIM  256
#define FDIM  4096
#define NEXP  8
#define MAXTILES 96
#define MAXSLOTS 16384
#define IMG   16384   // elements per 32 KB image

__device__ __forceinline__ bf16_t f2bf(float f) {
  union { float f; unsigned u; } a; a.f = f;
  unsigned u = a.u;
  return (bf16_t)((u + 0x7FFFu + ((u >> 16) & 1u)) >> 16);  // RNE
}

__device__ __forceinline__ float gelu_erf(float v) {
  return 0.5f * v * (1.0f + erff(v * 0.70710678118654752f));
}

__device__ __forceinline__ void gload16(const void* g, void* l) {
  __builtin_amdgcn_global_load_lds(
      (const __attribute__((address_space(1))) void*)g,
      (__attribute__((address_space(3))) void*)l, 16, 0, 0);
}

// swizzled in-image element offset for (row r, k index kl)
__device__ __forceinline__ int swz_off(int r, int kl) {
  return r * 128 + ((((kl >> 3) ^ (r & 15)) << 3) | (kl & 7));
}

// ---------------------------------------------------------------- packing

// one block packs one 128x128 image: src elem (kl, rr) = src[kl*kStride + rr]
__device__ __forceinline__ void pack_tile_body(const float* __restrict__ src,
                                               size_t kStride,
                                               bf16_t* __restrict__ img) {
  __shared__ bf16_t lim[IMG];
  const int tid = threadIdx.x;
  const int rr = tid & 127, half = tid >> 7;
  for (int kl = half; kl < 128; kl += 2)
    lim[swz_off(rr, kl)] = f2bf(src[(size_t)kl * kStride + rr]);
  __syncthreads();
  const int4* s4 = (const int4*)lim;
  int4* d4 = (int4*)img;
#pragma unroll
  for (int i = 0; i < 8; i++) d4[tid + i * 256] = s4[tid + i * 256];
}

// w1p images [e][nc][kb] (e*16+nc*8+kb): rows = rank nc*128+rr, k = h kb*128+kl
__global__ void pack_w1(const float* __restrict__ w1, bf16_t* __restrict__ w1p) {
  const int img = blockIdx.x;
  const int e = img >> 4, nc = (img >> 3) & 1, kb = img & 7;
  pack_tile_body(w1 + (size_t)e * 1024 * 256 + (size_t)kb * 128 * 256 + nc * 128,
                 256, w1p + (size_t)img * IMG);
}
// w2p images [n][e][kb] (n*16+e*2+kb): rows = f n*128+rr, k = rank kb*128+kl
__global__ void pack_w2(const float* __restrict__ w2, bf16_t* __restrict__ w2p) {
  const int img = blockIdx.x;
  const int n = img >> 4, e = (img >> 1) & 7, kb = img & 1;
  pack_tile_body(w2 + (size_t)e * 256 * 4096 + (size_t)kb * 128 * 4096 + n * 128,
                 4096, w2p + (size_t)img * IMG);
}
// ltwp images [n][kb] (n*32+kb): rows = h n*128+rr, k = f kb*128+kl
__global__ void pack_ltw(const float* __restrict__ l2w, bf16_t* __restrict__ ltwp) {
  const int img = blockIdx.x;
  const int n = img >> 5, kb = img & 31;
  pack_tile_body(l2w + (size_t)kb * 128 * 1024 + n * 128, 1024,
                 ltwp + (size_t)img * IMG);
}

// ---------------------------------------------------------------- routing
// ctrl ints: [64..127] bin_fill, [128..191] bin_start, [192] n_tiles,
//            [256 + 3t ..] meta{gid, slot0, nrows}

__global__ void router_kernel(const float* __restrict__ x,
                              const float* __restrict__ rw,
                              const float* __restrict__ rb,
                              int* __restrict__ gid_tok,
                              float2* __restrict__ tokscale,
                              bf16_t* __restrict__ xb) {
  const int token = blockIdx.x * 4 + (threadIdx.x >> 6);
  const int lane  = threadIdx.x & 63;
  const float* xr = x + (size_t)token * HDIM;
  bf16_t* xbr = xb + (size_t)token * HDIM;

  double acc[NEXP];
#pragma unroll
  for (int e = 0; e < NEXP; e++) acc[e] = 0.0;
  for (int h = lane; h < HDIM; h += 64) {
    const float xf = xr[h];
    xbr[h] = f2bf(xf);
    const double xv = (double)xf;
    const float* wr = rw + (size_t)h * NEXP;
#pragma unroll
    for (int e = 0; e < NEXP; e++) acc[e] += xv * (double)wr[e];
  }
#pragma unroll
  for (int off = 32; off > 0; off >>= 1) {
#pragma unroll
    for (int e = 0; e < NEXP; e++) acc[e] += __shfl_xor(acc[e], off, 64);
  }
  double lg[NEXP];
#pragma unroll
  for (int e = 0; e < NEXP; e++) lg[e] = acc[e] + (double)rb[e];

  double mx = lg[0];
#pragma unroll
  for (int e = 1; e < NEXP; e++) mx = fmax(mx, lg[e]);
  double p[NEXP]; double den = 0.0;
#pragma unroll
  for (int e = 0; e < NEXP; e++) { p[e] = exp(lg[e] - mx); den += p[e]; }

  int i1 = 0;
#pragma unroll
  for (int e = 1; e < NEXP; e++) if (lg[e] > lg[i1]) i1 = e;
  int i2 = (i1 == 0) ? 1 : 0;
#pragma unroll
  for (int e = 0; e < NEXP; e++)
    if (e != i1 && e != i2 && lg[e] > lg[i2]) i2 = e;

  if (lane == 0) {
    const int elo = min(i1, i2), ehi = max(i1, i2);
    gid_tok[token] = elo * 8 + ehi;
    tokscale[token] = make_float2((float)(p[elo] / den), (float)(p[ehi] / den));
  }
}

__global__ void build_tiles(const int* __restrict__ gid_tok,
                            int* __restrict__ ctrl,
                            int* __restrict__ tok_of_slot,
                            float2* __restrict__ scale_of_slot) {
  __shared__ int hist[64], ntl[64];
  const int t = threadIdx.x;
  for (int i = t; i < MAXSLOTS; i += 256) {
    tok_of_slot[i] = -1;
    scale_of_slot[i] = make_float2(0.f, 0.f);
  }
  if (t < 64) hist[t] = 0;
  __syncthreads();
  for (int i = t; i < TOK; i += 256) atomicAdd(&hist[gid_tok[i]], 1);
  __syncthreads();
  if (t < 64) ntl[t] = (hist[t] + 127) >> 7;
  __syncthreads();
  if (t < 64) {
    int slot0 = 0, tile0 = 0;
    for (int g = 0; g < t; g++) { slot0 += ntl[g] << 7; tile0 += ntl[g]; }
    ctrl[64 + t] = 0;        // bin_fill
    ctrl[128 + t] = slot0;   // bin_start
    const int nt = ntl[t], c = hist[t];
    for (int i = 0; i < nt; i++) {
      ctrl[256 + (tile0 + i) * 3 + 0] = t;
      ctrl[256 + (tile0 + i) * 3 + 1] = slot0 + i * 128;
      ctrl[256 + (tile0 + i) * 3 + 2] = min(128, c - i * 128);
    }
    if (t == 63) ctrl[192] = tile0 + nt;
  }
}

__global__ void scatter_tokens(const int* __restrict__ gid_tok,
                               const float2* __restrict__ tokscale,
                               int* __restrict__ ctrl,
                               int* __restrict__ tok_of_slot,
                               float2* __restrict__ scale_of_slot) {
  const int t = blockIdx.x * 256 + threadIdx.x;
  const int g = gid_tok[t];
  const int pos = atomicAdd(&ctrl[64 + g], 1);
  const int slot = ctrl[128 + g] + pos;
  tok_of_slot[slot] = t;
  scale_of_slot[slot] = tokscale[t];
}

// ---------------------------------------------------------------- GEMMs
// All: 128x128 output tile, BK=128, LDS = As(32K)+Bs(32K), 4 waves 2x2.
// Staging: wave w fills rows [w*32, w*32+32) of its image half = 8 KB = 8
// gload16 calls of 1 KB (lane l -> row w*32+i*4+(l>>4), phys granule l&15).
// Fragment (kstep s): granule (s*4+quad) ^ l16 of row base+l16 -> conflict-free.

// G1: Tp[tile][nt] image = xb[tok rows] @ w1p[e][nc] * scale
// grid 4*ntiles padded: b = tile*4 + nt ; nt: e = nt>>1, nc = nt&1
__global__ __launch_bounds__(256)
void gemm_g1(const bf16_t* __restrict__ xb, const bf16_t* __restrict__ w1p,
             bf16_t* __restrict__ Tp, const int* __restrict__ ctrl,
             const int* __restrict__ tok_of_slot,
             const float2* __restrict__ scale_of_slot) {
  const int b = blockIdx.x;
  const int tile = b >> 2, nt = b & 3;
  if (tile >= ctrl[192]) return;
  __shared__ bf16_t As[IMG];
  __shared__ bf16_t Bs[IMG];
  const int gid   = ctrl[256 + tile * 3];
  const int slot0 = ctrl[256 + tile * 3 + 1];
  const int e = (nt < 2) ? (gid >> 3) : (gid & 7);
  const int nc = nt & 1;
  const int tid = threadIdx.x, lane = tid & 63, w = tid >> 6;
  const int wm = (w >> 1) * 64, wn = (w & 1) * 64;
  const int l16 = lane & 15, quad = lane >> 4;

  floatx4 acc[4][4];
  const floatx4 zero = {0.f, 0.f, 0.f, 0.f};
#pragma unroll
  for (int i = 0; i < 4; i++)
#pragma unroll
    for (int j = 0; j < 4; j++) acc[i][j] = zero;

  int toks[8];
#pragma unroll
  for (int i = 0; i < 8; i++) {
    int tk = tok_of_slot[slot0 + w * 32 + i * 4 + (lane >> 4)];
    toks[i] = (tk < 0) ? 0 : tk;
  }
  const bf16_t* bimg = w1p + (size_t)(e * 16 + nc * 8) * IMG;
  bf16_t* lA = As + w * 4096;
  bf16_t* lB = Bs + w * 4096;

  for (int kb = 0; kb < 8; kb++) {
    __syncthreads();
#pragma unroll
    for (int i = 0; i < 8; i++) {
      const int g = (lane & 15) ^ ((i * 4 + (lane >> 4)) & 15);
      gload16(xb + (size_t)toks[i] * HDIM + kb * 128 + g * 8, lA + i * 512);
      gload16(bimg + (size_t)kb * IMG + w * 4096 + i * 512 + lane * 8, lB + i * 512);
    }
    __syncthreads();
#pragma unroll
    for (int s = 0; s < 4; s++) {
      const int pg = ((s * 4 + quad) ^ l16) << 3;
      short8 af[4], bfr[4];
#pragma unroll
      for (int i = 0; i < 4; i++) {
        af[i]  = *(const short8*)&As[(wm + i * 16 + l16) * 128 + pg];
        bfr[i] = *(const short8*)&Bs[(wn + i * 16 + l16) * 128 + pg];
      }
#pragma unroll
      for (int mi = 0; mi < 4; mi++)
#pragma unroll
        for (int ni = 0; ni < 4; ni++)
          acc[mi][ni] = __builtin_amdgcn_mfma_f32_16x16x32_bf16(
              af[mi], bfr[ni], acc[mi][ni], 0, 0, 0);
    }
  }

  bf16_t* img = Tp + (size_t)(tile * 4 + nt) * IMG;
#pragma unroll
  for (int mi = 0; mi < 4; mi++) {
#pragma unroll
    for (int r = 0; r < 4; r++) {
      const int rl = wm + mi * 16 + quad * 4 + r;
      const float2 sc = scale_of_slot[slot0 + rl];
      const float s = (nt < 2) ? sc.x : sc.y;
#pragma unroll
      for (int ni = 0; ni < 4; ni++) {
        const int c = wn + ni * 16 + l16;
        img[swz_off(rl, c)] = f2bf(acc[mi][ni][r] * s);
      }
    }
  }
}

// G2: Hbp images = gelu(Tp[tile] @ w2p[n][pair]) ; b = tile*32 + n
__global__ __launch_bounds__(256)
void gemm_g2(const bf16_t* __restrict__ Tp, const bf16_t* __restrict__ w2p,
             bf16_t* __restrict__ Hbp, const int* __restrict__ ctrl,
             const int* __restrict__ tok_of_slot) {
  const int b = blockIdx.x;
  const int tile = b >> 5, n = b & 31;
  if (tile >= ctrl[192]) return;
  __shared__ bf16_t As[IMG];
  __shared__ bf16_t Bs[IMG];
  const int gid   = ctrl[256 + tile * 3];
  const int slot0 = ctrl[256 + tile * 3 + 1];
  const int elo = gid >> 3, ehi = gid & 7;
  const int tid = threadIdx.x, lane = tid & 63, w = tid >> 6;
  const int wm = (w >> 1) * 64, wn = (w & 1) * 64;
  const int l16 = lane & 15, quad = lane >> 4;

  floatx4 acc[4][4];
  const floatx4 zero = {0.f, 0.f, 0.f, 0.f};
#pragma unroll
  for (int i = 0; i < 4; i++)
#pragma unroll
    for (int j = 0; j < 4; j++) acc[i][j] = zero;

  const bf16_t* aimg = Tp + (size_t)tile * 4 * IMG;
  bf16_t* lA = As + w * 4096;
  bf16_t* lB = Bs + w * 4096;

#pragma unroll
  for (int t = 0; t < 4; t++) {
    const int e = (t < 2) ? elo : ehi;
    const bf16_t* bimg = w2p + (size_t)(n * 16 + e * 2 + (t & 1)) * IMG;
    __syncthreads();
#pragma unroll
    for (int i = 0; i < 8; i++) {
      gload16(aimg + (size_t)t * IMG + w * 4096 + i * 512 + lane * 8, lA + i * 512);
      gload16(bimg + w * 4096 + i * 512 + lane * 8, lB + i * 512);
    }
    __syncthreads();
#pragma unroll
    for (int s = 0; s < 4; s++) {
      const int pg = ((s * 4 + quad) ^ l16) << 3;
      short8 af[4], bfr[4];
#pragma unroll
      for (int i = 0; i < 4; i++) {
        af[i]  = *(const short8*)&As[(wm + i * 16 + l16) * 128 + pg];
        bfr[i] = *(const short8*)&Bs[(wn + i * 16 + l16) * 128 + pg];
      }
#pragma unroll
      for (int mi = 0; mi < 4; mi++)
#pragma unroll
        for (int ni = 0; ni < 4; ni++)
          acc[mi][ni] = __builtin_amdgcn_mfma_f32_16x16x32_bf16(
              af[mi], bfr[ni], acc[mi][ni], 0, 0, 0);
    }
  }

#pragma unroll
  for (int mi = 0; mi < 4; mi++) {
#pragma unroll
    for (int r = 0; r < 4; r++) {
      const int srow = slot0 + wm + mi * 16 + quad * 4 + r;
      const int tok = tok_of_slot[srow];
      if (tok < 0) continue;
      bf16_t* img = Hbp + (size_t)((tok >> 7) * 32 + n) * IMG;
      const int rloc = tok & 127;
#pragma unroll
      for (int ni = 0; ni < 4; ni++) {
        const int kl = wn + ni * 16 + l16;
        img[swz_off(rloc, kl)] = f2bf(gelu_erf(acc[mi][ni][r]));
      }
    }
  }
}

// G3: out = Hbp @ ltwp^T + bias ; XCD-owned M groups (r5-validated mapping):
// xcd = b&7 owns M-tiles [8*xcd, 8*xcd+8) ; msub = (b>>3)&7 ; n = b>>6
__global__ __launch_bounds__(256)
void gemm_g3(const bf16_t* __restrict__ Hbp, const bf16_t* __restrict__ ltwp,
             float* __restrict__ out, const float* __restrict__ bias) {
  __shared__ bf16_t As[IMG];
  __shared__ bf16_t Bs[IMG];
  const int b = blockIdx.x;
  const int mtile = (b & 7) * 8 + ((b >> 3) & 7);
  const int n = b >> 6;
  const int tid = threadIdx.x, lane = tid & 63, w = tid >> 6;
  const int wm = (w >> 1) * 64, wn = (w & 1) * 64;
  const int l16 = lane & 15, quad = lane >> 4;

  floatx4 acc[4][4];
  const floatx4 zero = {0.f, 0.f, 0.f, 0.f};
#pragma unroll
  for (int i = 0; i < 4; i++)
#pragma unroll
    for (int j = 0; j < 4; j++) acc[i][j] = zero;

  const bf16_t* aimg = Hbp + (size_t)mtile * 32 * IMG;
  const bf16_t* bimg = ltwp + (size_t)n * 32 * IMG;
  bf16_t* lA = As + w * 4096;
  bf16_t* lB = Bs + w * 4096;

  for (int kb = 0; kb < 32; kb++) {
    __syncthreads();
#pragma unroll
    for (int i = 0; i < 8; i++) {
      gload16(aimg + (size_t)kb * IMG + w * 4096 + i * 512 + lane * 8, lA + i * 512);
      gload16(bimg + (size_t)kb * IMG + w * 4096 + i * 512 + lane * 8, lB + i * 512);
    }
    __syncthreads();
#pragma unroll
    for (int s = 0; s < 4; s++) {
      const int pg = ((s * 4 + quad) ^ l16) << 3;
      short8 af[4], bfr[4];
#pragma unroll
      for (int i = 0; i < 4; i++) {
        af[i]  = *(const short8*)&As[(wm + i * 16 + l16) * 128 + pg];
        bfr[i] = *(const short8*)&Bs[(wn + i * 16 + l16) * 128 + pg];
      }
#pragma unroll
      for (int mi = 0; mi < 4; mi++)
#pragma unroll
        for (int ni = 0; ni < 4; ni++)
          acc[mi][ni] = __builtin_amdgcn_mfma_f32_16x16x32_bf16(
              af[mi], bfr[ni], acc[mi][ni], 0, 0, 0);
    }
  }

#pragma unroll
  for (int mi = 0; mi < 4; mi++) {
#pragma unroll
    for (int ni = 0; ni < 4; ni++) {
      const int row = mtile * 128 + wm + mi * 16 + quad * 4;
      const int col = n * 128 + wn + ni * 16 + l16;
#pragma unroll
      for (int r = 0; r < 4; r++)
        out[(size_t)(row + r) * HDIM + col] = acc[mi][ni][r] + bias[col];
    }
  }
}

// ---------------------------------------------------------------- launch

extern "C" void kernel_launch(void* const* d_in, const int* in_sizes, int n_in,
                              void* d_out, int out_size, void* d_ws, size_t ws_size,
                              hipStream_t stream) {
  const float* x   = (const float*)d_in[0];
  const float* rw  = (const float*)d_in[1];
  const float* rb  = (const float*)d_in[2];
  const float* w1  = (const float*)d_in[3];
  const float* w2  = (const float*)d_in[4];
  const float* l2w = (const float*)d_in[5];
  const float* l2b = (const float*)d_in[6];

  char* ws = (char*)d_ws;
  int*    ctrl     = (int*)   (ws + 0);          //   4 KB
  int*    gid_tok  = (int*)   (ws + 4096);       //  32 KB
  float2* tokscale = (float2*)(ws + 36864);      //  64 KB
  int*    tokslot  = (int*)   (ws + 102400);     //  64 KB
  float2* slotsc   = (float2*)(ws + 167936);     // 128 KB
  bf16_t* xb   = (bf16_t*)(ws + 1048576);        // 16.78 MB
  bf16_t* w1p  = (bf16_t*)(ws + 17825792);       //  4.19 MB (128 images)
  bf16_t* w2p  = (bf16_t*)(ws + 22020096);       // 16.78 MB (512 images)
  bf16_t* ltwp = (bf16_t*)(ws + 38797312);       //  8.39 MB (256 images)
  bf16_t* Tp   = (bf16_t*)(ws + 47185920);       // 12.58 MB (96*4 images)
  bf16_t* Hbp  = (bf16_t*)(ws + 59768832);       // 67.11 MB (64*32 images) -> end 126,877,696

  // routing (router also emits xb)
  router_kernel<<<TOK / 4, 256, 0, stream>>>(x, rw, rb, gid_tok, tokscale, xb);
  build_tiles<<<1, 256, 0, stream>>>(gid_tok, ctrl, tokslot, slotsc);
  scatter_tokens<<<TOK / 256, 256, 0, stream>>>(gid_tok, tokscale, ctrl, tokslot, slotsc);

  // weight packing (pre-swizzled LDS images)
  pack_w1<<<128, 256, 0, stream>>>(w1, w1p);
  pack_w2<<<512, 256, 0, stream>>>(w2, w2p);
  pack_ltw<<<256, 256, 0, stream>>>(l2w, ltwp);

  // routed GEMMs + dense output GEMM
  gemm_g1<<<4 * MAXTILES, 256, 0, stream>>>(xb, w1p, Tp, ctrl, tokslot, slotsc);
  gemm_g2<<<32 * MAXTILES, 256, 0, stream>>>(Tp, w2p, Hbp, ctrl, tokslot);
  gemm_g3<<<512, 256, 0, stream>>>(Hbp, ltwp, (float*)d_out, l2b);
}

// Round 7
// 354.132 us; speedup vs baseline: 1.0605x; 1.0605x over previous
//
#include <hip/hip_runtime.h>
#include <math.h>

// MoE FFN, routed (top-2 pair-grouped), mixed layout:
//   Tp (G1 out / G2 A-operand): pre-swizzled 32 KB images [128 x 128]
//   Hb (G2 out / G3 A-operand): plain row-major [tok][4096]
//   G1: 64x128 BK=128 (images in/out)     G2: 64x128 BK=128 (image A, row out)
//   G3: 128x128 BK=64 strided (round-5 version, ~800 TF)
// Image swizzle: elem(r,k) at r*128 + (((k>>3)^(r&15))<<3 | (k&7)).

using short8  = __attribute__((ext_vector_type(8))) short;
using floatx4 = __attribute__((ext_vector_type(4))) float;
typedef unsigned short bf16_t;

#define TOK   8192
#define HDIM  1024
#define RDIM  256
#define FDIM  4096
#define NEXP  8
#define MAXTILES 96
#define MAXSLOTS 16384
#define IMG   16384

__device__ __forceinline__ bf16_t f2bf(float f) {
  union { float f; unsigned u; } a; a.f = f;
  unsigned u = a.u;
  return (bf16_t)((u + 0x7FFFu + ((u >> 16) & 1u)) >> 16);  // RNE
}

__device__ __forceinline__ float gelu_erf(float v) {
  return 0.5f * v * (1.0f + erff(v * 0.70710678118654752f));
}

__device__ __forceinline__ void gload16(const void* g, void* l) {
  __builtin_amdgcn_global_load_lds(
      (const __attribute__((address_space(1))) void*)g,
      (__attribute__((address_space(3))) void*)l, 16, 0, 0);
}

__device__ __forceinline__ int swz_off(int r, int kl) {
  return r * 128 + ((((kl >> 3) ^ (r & 15)) << 3) | (kl & 7));
}

// ---------------------------------------------------------------- packing

__device__ __forceinline__ void pack_tile_body(const float* __restrict__ src,
                                               size_t kStride,
                                               bf16_t* __restrict__ img) {
  __shared__ bf16_t lim[IMG];
  const int tid = threadIdx.x;
  const int rr = tid & 127, half = tid >> 7;
  for (int kl = half; kl < 128; kl += 2)
    lim[swz_off(rr, kl)] = f2bf(src[(size_t)kl * kStride + rr]);
  __syncthreads();
  const int4* s4 = (const int4*)lim;
  int4* d4 = (int4*)img;
#pragma unroll
  for (int i = 0; i < 8; i++) d4[tid + i * 256] = s4[tid + i * 256];
}

// w1p [e][nc][kb]: rows = rank nc*128+rr, k = h kb*128+kl
__global__ void pack_w1(const float* __restrict__ w1, bf16_t* __restrict__ w1p) {
  const int img = blockIdx.x;
  const int e = img >> 4, nc = (img >> 3) & 1, kb = img & 7;
  pack_tile_body(w1 + (size_t)e * 1024 * 256 + (size_t)kb * 128 * 256 + nc * 128,
                 256, w1p + (size_t)img * IMG);
}
// w2p [n][e][kb]: rows = f n*128+rr, k = rank kb*128+kl
__global__ void pack_w2(const float* __restrict__ w2, bf16_t* __restrict__ w2p) {
  const int img = blockIdx.x;
  const int n = img >> 4, e = (img >> 1) & 7, kb = img & 1;
  pack_tile_body(w2 + (size_t)e * 256 * 4096 + (size_t)kb * 128 * 4096 + n * 128,
                 4096, w2p + (size_t)img * IMG);
}

// transpose+convert (for lin2_w -> ltw[h][f], row-major bf16)
__global__ void tcvt(const float* __restrict__ in, bf16_t* __restrict__ out,
                     int cols, size_t inSlice, size_t ldo,
                     int outRowStep, int outColStep) {
  __shared__ float tile[64][65];
  const int z  = blockIdx.z;
  const float* src = in + (size_t)z * inSlice;
  const int c0 = blockIdx.x * 64;
  const int r0 = blockIdx.y * 64;
  const int tx = threadIdx.x;
  const int ty = threadIdx.y;
#pragma unroll
  for (int i = 0; i < 64; i += 4)
    tile[ty + i][tx] = src[(size_t)(r0 + ty + i) * cols + (c0 + tx)];
  __syncthreads();
#pragma unroll
  for (int i = 0; i < 64; i += 4) {
    float v = tile[tx][ty + i];
    out[((size_t)(c0 + ty + i) + (size_t)z * outRowStep) * ldo +
        (size_t)z * outColStep + (r0 + tx)] = f2bf(v);
  }
}

// ---------------------------------------------------------------- routing

__global__ void router_kernel(const float* __restrict__ x,
                              const float* __restrict__ rw,
                              const float* __restrict__ rb,
                              int* __restrict__ gid_tok,
                              float2* __restrict__ tokscale,
                              bf16_t* __restrict__ xb) {
  const int token = blockIdx.x * 4 + (threadIdx.x >> 6);
  const int lane  = threadIdx.x & 63;
  const float* xr = x + (size_t)token * HDIM;
  bf16_t* xbr = xb + (size_t)token * HDIM;

  double acc[NEXP];
#pragma unroll
  for (int e = 0; e < NEXP; e++) acc[e] = 0.0;
  for (int h = lane; h < HDIM; h += 64) {
    const float xf = xr[h];
    xbr[h] = f2bf(xf);
    const double xv = (double)xf;
    const float* wr = rw + (size_t)h * NEXP;
#pragma unroll
    for (int e = 0; e < NEXP; e++) acc[e] += xv * (double)wr[e];
  }
#pragma unroll
  for (int off = 32; off > 0; off >>= 1) {
#pragma unroll
    for (int e = 0; e < NEXP; e++) acc[e] += __shfl_xor(acc[e], off, 64);
  }
  double lg[NEXP];
#pragma unroll
  for (int e = 0; e < NEXP; e++) lg[e] = acc[e] + (double)rb[e];

  double mx = lg[0];
#pragma unroll
  for (int e = 1; e < NEXP; e++) mx = fmax(mx, lg[e]);
  double p[NEXP]; double den = 0.0;
#pragma unroll
  for (int e = 0; e < NEXP; e++) { p[e] = exp(lg[e] - mx); den += p[e]; }

  int i1 = 0;
#pragma unroll
  for (int e = 1; e < NEXP; e++) if (lg[e] > lg[i1]) i1 = e;
  int i2 = (i1 == 0) ? 1 : 0;
#pragma unroll
  for (int e = 0; e < NEXP; e++)
    if (e != i1 && e != i2 && lg[e] > lg[i2]) i2 = e;

  if (lane == 0) {
    const int elo = min(i1, i2), ehi = max(i1, i2);
    gid_tok[token] = elo * 8 + ehi;
    tokscale[token] = make_float2((float)(p[elo] / den), (float)(p[ehi] / den));
  }
}

__global__ void build_tiles(const int* __restrict__ gid_tok,
                            int* __restrict__ ctrl,
                            int* __restrict__ tok_of_slot,
                            float2* __restrict__ scale_of_slot) {
  __shared__ int hist[64], ntl[64];
  const int t = threadIdx.x;
  for (int i = t; i < MAXSLOTS; i += 256) {
    tok_of_slot[i] = -1;
    scale_of_slot[i] = make_float2(0.f, 0.f);
  }
  if (t < 64) hist[t] = 0;
  __syncthreads();
  for (int i = t; i < TOK; i += 256) atomicAdd(&hist[gid_tok[i]], 1);
  __syncthreads();
  if (t < 64) ntl[t] = (hist[t] + 127) >> 7;
  __syncthreads();
  if (t < 64) {
    int slot0 = 0, tile0 = 0;
    for (int g = 0; g < t; g++) { slot0 += ntl[g] << 7; tile0 += ntl[g]; }
    ctrl[64 + t] = 0;
    ctrl[128 + t] = slot0;
    const int nt = ntl[t], c = hist[t];
    for (int i = 0; i < nt; i++) {
      ctrl[256 + (tile0 + i) * 3 + 0] = t;
      ctrl[256 + (tile0 + i) * 3 + 1] = slot0 + i * 128;
      ctrl[256 + (tile0 + i) * 3 + 2] = min(128, c - i * 128);
    }
    if (t == 63) ctrl[192] = tile0 + nt;
  }
}

__global__ void scatter_tokens(const int* __restrict__ gid_tok,
                               const float2* __restrict__ tokscale,
                               int* __restrict__ ctrl,
                               int* __restrict__ tok_of_slot,
                               float2* __restrict__ scale_of_slot) {
  const int t = blockIdx.x * 256 + threadIdx.x;
  const int g = gid_tok[t];
  const int pos = atomicAdd(&ctrl[64 + g], 1);
  const int slot = ctrl[128 + g] + pos;
  tok_of_slot[slot] = t;
  scale_of_slot[slot] = tokscale[t];
}

// ---------------------------------------------------------------- G1
// 64x128 tile, BK=128. As = 64x128 (16 KB, gathered from xb, XOR-placed),
// Bs = full w1p image (32 KB, sequential). LDS 48 KB -> 3 blocks/CU.
// b: tile = b>>3, mh = (b>>2)&1, n = b&3. Writes half of Tp image tile*4+n.
__global__ __launch_bounds__(256)
void gemm_g1(const bf16_t* __restrict__ xb, const bf16_t* __restrict__ w1p,
             bf16_t* __restrict__ Tp, const int* __restrict__ ctrl,
             const int* __restrict__ tok_of_slot,
             const float2* __restrict__ scale_of_slot) {
  const int b = blockIdx.x;
  const int tile = b >> 3, mh = (b >> 2) & 1, n = b & 3;
  if (tile >= ctrl[192]) return;
  const int nrows = ctrl[256 + tile * 3 + 2];
  if (mh && nrows <= 64) return;
  __shared__ bf16_t As[64 * 128];
  __shared__ bf16_t Bs[128 * 128];
  const int gid   = ctrl[256 + tile * 3];
  const int slot0 = ctrl[256 + tile * 3 + 1];
  const int e = (n < 2) ? (gid >> 3) : (gid & 7);
  const int nc = n & 1;
  const int tid = threadIdx.x, lane = tid & 63, w = tid >> 6;
  const int wm = (w & 1) * 32, wn = (w >> 1) * 64;
  const int l16 = lane & 15, quad = lane >> 4;

  floatx4 acc[2][4];
  const floatx4 zero = {0.f, 0.f, 0.f, 0.f};
#pragma unroll
  for (int i = 0; i < 2; i++)
#pragma unroll
    for (int j = 0; j < 4; j++) acc[i][j] = zero;

  // A gather setup: wave stages rows w*16 + i*4 + (lane>>4), i=0..3
  int toks[4];
  int rowAs[4];
#pragma unroll
  for (int i = 0; i < 4; i++) {
    rowAs[i] = w * 16 + i * 4 + (lane >> 4);
    int tk = tok_of_slot[slot0 + mh * 64 + rowAs[i]];
    toks[i] = (tk < 0) ? 0 : tk;
  }
  const bf16_t* bimg = w1p + (size_t)(e * 16 + nc * 8) * IMG;
  bf16_t* lA = As + w * 2048;
  bf16_t* lB = Bs + w * 4096;

  for (int kb = 0; kb < 8; kb++) {
    __syncthreads();
#pragma unroll
    for (int i = 0; i < 4; i++) {
      const int gq = (lane & 15) ^ (rowAs[i] & 15);
      gload16(xb + (size_t)toks[i] * HDIM + kb * 128 + gq * 8, lA + i * 512);
    }
#pragma unroll
    for (int i = 0; i < 8; i++)
      gload16(bimg + (size_t)kb * IMG + w * 4096 + i * 512 + lane * 8, lB + i * 512);
    __syncthreads();
#pragma unroll
    for (int s = 0; s < 4; s++) {
      const int pg = ((s * 4 + quad) ^ l16) << 3;
      short8 af[2], bfr[4];
#pragma unroll
      for (int i = 0; i < 2; i++)
        af[i] = *(const short8*)&As[(wm + i * 16 + l16) * 128 + pg];
#pragma unroll
      for (int i = 0; i < 4; i++)
        bfr[i] = *(const short8*)&Bs[(wn + i * 16 + l16) * 128 + pg];
#pragma unroll
      for (int mi = 0; mi < 2; mi++)
#pragma unroll
        for (int ni = 0; ni < 4; ni++)
          acc[mi][ni] = __builtin_amdgcn_mfma_f32_16x16x32_bf16(
              af[mi], bfr[ni], acc[mi][ni], 0, 0, 0);
    }
  }

  // stage C (scaled, bf16, swizzled) into As, then sequential 16 KB copy-out
  __syncthreads();
#pragma unroll
  for (int mi = 0; mi < 2; mi++) {
#pragma unroll
    for (int r = 0; r < 4; r++) {
      const int rloc = wm + mi * 16 + quad * 4 + r;
      const float2 sc = scale_of_slot[slot0 + mh * 64 + rloc];
      const float s = (n < 2) ? sc.x : sc.y;
#pragma unroll
      for (int ni = 0; ni < 4; ni++) {
        const int c = wn + ni * 16 + l16;
        As[swz_off(rloc, c)] = f2bf(acc[mi][ni][r] * s);
      }
    }
  }
  __syncthreads();
  bf16_t* img = Tp + (size_t)(tile * 4 + n) * IMG + mh * 64 * 128;
  const int4* s4 = (const int4*)As;
  int4* d4 = (int4*)img;
#pragma unroll
  for (int j = 0; j < 4; j++) d4[tid + j * 256] = s4[tid + j * 256];
}

// ---------------------------------------------------------------- G2
// 64x128 tile, BK=128. As = half Tp image (16 KB seq), Bs = w2p image (32 KB
// seq). LDS 48 KB -> 3 blocks/CU. Epilogue: gelu -> row-major LDS -> 256 B
// coalesced bursts to token rows of Hb.
// b: tile = b>>6, mh = (b>>5)&1, n = b&31.
__global__ __launch_bounds__(256)
void gemm_g2(const bf16_t* __restrict__ Tp, const bf16_t* __restrict__ w2p,
             bf16_t* __restrict__ Hb, const int* __restrict__ ctrl,
             const int* __restrict__ tok_of_slot) {
  const int b = blockIdx.x;
  const int tile = b >> 6, mh = (b >> 5) & 1, n = b & 31;
  if (tile >= ctrl[192]) return;
  const int nrows = ctrl[256 + tile * 3 + 2];
  if (mh && nrows <= 64) return;
  __shared__ bf16_t As[64 * 128];
  __shared__ bf16_t Bs[128 * 128];
  const int gid   = ctrl[256 + tile * 3];
  const int slot0 = ctrl[256 + tile * 3 + 1];
  const int elo = gid >> 3, ehi = gid & 7;
  const int tid = threadIdx.x, lane = tid & 63, w = tid >> 6;
  const int wm = (w & 1) * 32, wn = (w >> 1) * 64;
  const int l16 = lane & 15, quad = lane >> 4;

  floatx4 acc[2][4];
  const floatx4 zero = {0.f, 0.f, 0.f, 0.f};
#pragma unroll
  for (int i = 0; i < 2; i++)
#pragma unroll
    for (int j = 0; j < 4; j++) acc[i][j] = zero;

  const bf16_t* aimg = Tp + (size_t)tile * 4 * IMG + mh * 64 * 128;
  bf16_t* lA = As + w * 2048;
  bf16_t* lB = Bs + w * 4096;

#pragma unroll
  for (int t = 0; t < 4; t++) {
    const int e = (t < 2) ? elo : ehi;
    const bf16_t* bimg = w2p + (size_t)(n * 16 + e * 2 + (t & 1)) * IMG;
    __syncthreads();
#pragma unroll
    for (int i = 0; i < 4; i++)
      gload16(aimg + (size_t)t * IMG + w * 2048 + i * 512 + lane * 8, lA + i * 512);
#pragma unroll
    for (int i = 0; i < 8; i++)
      gload16(bimg + w * 4096 + i * 512 + lane * 8, lB + i * 512);
    __syncthreads();
#pragma unroll
    for (int s = 0; s < 4; s++) {
      const int pg = ((s * 4 + quad) ^ l16) << 3;
      short8 af[2], bfr[4];
#pragma unroll
      for (int i = 0; i < 2; i++)
        af[i] = *(const short8*)&As[(wm + i * 16 + l16) * 128 + pg];
#pragma unroll
      for (int i = 0; i < 4; i++)
        bfr[i] = *(const short8*)&Bs[(wn + i * 16 + l16) * 128 + pg];
#pragma unroll
      for (int mi = 0; mi < 2; mi++)
#pragma unroll
        for (int ni = 0; ni < 4; ni++)
          acc[mi][ni] = __builtin_amdgcn_mfma_f32_16x16x32_bf16(
              af[mi], bfr[ni], acc[mi][ni], 0, 0, 0);
    }
  }

  // epilogue: gelu -> Bs row-major [64][128] -> coalesced token-row bursts
  __syncthreads();
#pragma unroll
  for (int mi = 0; mi < 2; mi++) {
#pragma unroll
    for (int r = 0; r < 4; r++) {
      const int rloc = wm + mi * 16 + quad * 4 + r;
#pragma unroll
      for (int ni = 0; ni < 4; ni++) {
        const int c = wn + ni * 16 + l16;
        Bs[rloc * 128 + c] = f2bf(gelu_erf(acc[mi][ni][r]));
      }
    }
  }
  __syncthreads();
  const int4* s4 = (const int4*)Bs;
#pragma unroll
  for (int j = 0; j < 4; j++) {
    const int chunk = tid + j * 256;
    const int row = chunk >> 4, off = chunk & 15;
    const int tok = tok_of_slot[slot0 + mh * 64 + row];
    if (tok >= 0)
      *(int4*)(Hb + (size_t)tok * FDIM + n * 128 + off * 8) = s4[chunk];
  }
}

// ---------------------------------------------------------------- G3
// round-5 version: 128x128 BK=64 strided, 32 KB LDS, XCD-owned M groups.
__global__ __launch_bounds__(256)
void gemm_g3(const bf16_t* __restrict__ Hb, const bf16_t* __restrict__ ltw,
             float* __restrict__ out, const float* __restrict__ bias) {
  __shared__ bf16_t As[128 * 64];
  __shared__ bf16_t Bs[128 * 64];
  const int b = blockIdx.x;
  const int m0 = ((b & 7) * 8 + ((b >> 3) & 7)) * 128;
  const int n0 = (b >> 6) * 128;
  const int tid = threadIdx.x, lane = tid & 63, w = tid >> 6;
  const int wm = (w >> 1) * 64, wn = (w & 1) * 64;
  const int l16 = lane & 15, quad = lane >> 4;
  const int rl = lane >> 3, gg = lane & 7;
  const int gf = (gg ^ rl) * 8;

  floatx4 acc[4][4];
  const floatx4 zero = {0.f, 0.f, 0.f, 0.f};
#pragma unroll
  for (int i = 0; i < 4; i++)
#pragma unroll
    for (int j = 0; j < 4; j++) acc[i][j] = zero;

  const bf16_t* ga[4];
  const bf16_t* gb[4];
#pragma unroll
  for (int c = 0; c < 4; c++) {
    ga[c] = Hb  + (size_t)(m0 + w * 32 + c * 8 + rl) * FDIM + gf;
    gb[c] = ltw + (size_t)(n0 + w * 32 + c * 8 + rl) * FDIM + gf;
  }
  bf16_t* lA = &As[w * 32 * 64];
  bf16_t* lB = &Bs[w * 32 * 64];

  for (int k0 = 0; k0 < FDIM; k0 += 64) {
    __syncthreads();
#pragma unroll
    for (int c = 0; c < 4; c++) { gload16(ga[c], lA + c * 512); ga[c] += 64; }
#pragma unroll
    for (int c = 0; c < 4; c++) { gload16(gb[c], lB + c * 512); gb[c] += 64; }
    __syncthreads();
#pragma unroll
    for (int s = 0; s < 2; s++) {
      const int pg = ((s * 4 + quad) ^ (l16 & 7)) * 8;
      short8 af[4], bfr[4];
#pragma unroll
      for (int i = 0; i < 4; i++)
        af[i] = *(const short8*)&As[(wm + i * 16 + l16) * 64 + pg];
#pragma unroll
      for (int i = 0; i < 4; i++)
        bfr[i] = *(const short8*)&Bs[(wn + i * 16 + l16) * 64 + pg];
#pragma unroll
      for (int mi = 0; mi < 4; mi++)
#pragma unroll
        for (int ni = 0; ni < 4; ni++)
          acc[mi][ni] = __builtin_amdgcn_mfma_f32_16x16x32_bf16(
              af[mi], bfr[ni], acc[mi][ni], 0, 0, 0);
    }
  }

#pragma unroll
  for (int mi = 0; mi < 4; mi++) {
#pragma unroll
    for (int ni = 0; ni < 4; ni++) {
      const int row = m0 + wm + mi * 16 + quad * 4;
      const int col = n0 + wn + ni * 16 + l16;
#pragma unroll
      for (int r = 0; r < 4; r++)
        out[(size_t)(row + r) * HDIM + col] = acc[mi][ni][r] + bias[col];
    }
  }
}

// ---------------------------------------------------------------- launch

extern "C" void kernel_launch(void* const* d_in, const int* in_sizes, int n_in,
                              void* d_out, int out_size, void* d_ws, size_t ws_size,
                              hipStream_t stream) {
  const float* x   = (const float*)d_in[0];
  const float* rw  = (const float*)d_in[1];
  const float* rb  = (const float*)d_in[2];
  const float* w1  = (const float*)d_in[3];
  const float* w2  = (const float*)d_in[4];
  const float* l2w = (const float*)d_in[5];
  const float* l2b = (const float*)d_in[6];

  char* ws = (char*)d_ws;
  int*    ctrl     = (int*)   (ws + 0);
  int*    gid_tok  = (int*)   (ws + 4096);
  float2* tokscale = (float2*)(ws + 36864);
  int*    tokslot  = (int*)   (ws + 102400);
  float2* slotsc   = (float2*)(ws + 167936);
  bf16_t* xb  = (bf16_t*)(ws + 1048576);        // 16.78 MB
  bf16_t* w1p = (bf16_t*)(ws + 17825792);       //  4.19 MB (128 images)
  bf16_t* w2p = (bf16_t*)(ws + 22020096);       // 16.78 MB (512 images)
  bf16_t* ltw = (bf16_t*)(ws + 38797312);       //  8.39 MB (row-major [h][f])
  bf16_t* Tp  = (bf16_t*)(ws + 47185920);       // 12.58 MB (96*4 images)
  bf16_t* Hb  = (bf16_t*)(ws + 59768832);       // 67.11 MB -> end 126,877,696

  router_kernel<<<TOK / 4, 256, 0, stream>>>(x, rw, rb, gid_tok, tokscale, xb);
  build_tiles<<<1, 256, 0, stream>>>(gid_tok, ctrl, tokslot, slotsc);
  scatter_tokens<<<TOK / 256, 256, 0, stream>>>(gid_tok, tokscale, ctrl, tokslot, slotsc);

  pack_w1<<<128, 256, 0, stream>>>(w1, w1p);
  pack_w2<<<512, 256, 0, stream>>>(w2, w2p);
  tcvt<<<dim3(HDIM / 64, FDIM / 64, 1), dim3(64, 4), 0, stream>>>(
      l2w, ltw, HDIM, 0, FDIM, 0, 0);

  gemm_g1<<<8 * MAXTILES, 256, 0, stream>>>(xb, w1p, Tp, ctrl, tokslot, slotsc);
  gemm_g2<<<64 * MAXTILES, 256, 0, stream>>>(Tp, w2p, Hb, ctrl, tokslot);
  gemm_g3<<<512, 256, 0, stream>>>(Hb, ltw, (float*)d_out, l2b);
}